// Round 9
// baseline (593.578 us; speedup 1.0000x reference)
//
#include <hip/hip_runtime.h>
#include <cstdint>
#include <cstddef>

#define BB 64
#define TT 512
#define DD 1024
#define NTAG 64
#define SCORES_ELEMS (BB * TT * NTAG)      // 2097152
#define TAGS_OFF SCORES_ELEMS              // 2097152
#define LOSS_OFF (SCORES_ELEMS + BB * TT)  // 2130920

typedef __attribute__((ext_vector_type(8))) short short8;
typedef __attribute__((ext_vector_type(4))) float floatx4;

__device__ __forceinline__ float rl(float v, int i) {
  return __int_as_float(__builtin_amdgcn_readlane(__float_as_int(v), i));
}

__device__ __forceinline__ unsigned short f2bf_rne(float x) {
  const unsigned int u = __float_as_uint(x);
  const unsigned int r = u + 0x7FFFu + ((u >> 16) & 1u);
  return (unsigned short)(r >> 16);
}
__device__ __forceinline__ float bf2f(unsigned short h) {
  return __uint_as_float(((unsigned int)h) << 16);
}

// ---------------- DPP wave64 reductions ----------------
__device__ __forceinline__ float dpp_red_max(float v) {
  int x;
  x = __builtin_amdgcn_update_dpp(__float_as_int(v), __float_as_int(v), 0x111, 0xf, 0xf, false);
  v = fmaxf(v, __int_as_float(x));
  x = __builtin_amdgcn_update_dpp(__float_as_int(v), __float_as_int(v), 0x112, 0xf, 0xf, false);
  v = fmaxf(v, __int_as_float(x));
  x = __builtin_amdgcn_update_dpp(__float_as_int(v), __float_as_int(v), 0x114, 0xf, 0xf, false);
  v = fmaxf(v, __int_as_float(x));
  x = __builtin_amdgcn_update_dpp(__float_as_int(v), __float_as_int(v), 0x118, 0xf, 0xf, false);
  v = fmaxf(v, __int_as_float(x));
  x = __builtin_amdgcn_update_dpp(__float_as_int(v), __float_as_int(v), 0x142, 0xa, 0xf, false);
  v = fmaxf(v, __int_as_float(x));
  x = __builtin_amdgcn_update_dpp(__float_as_int(v), __float_as_int(v), 0x143, 0xc, 0xf, false);
  v = fmaxf(v, __int_as_float(x));
  return __int_as_float(__builtin_amdgcn_readlane(__float_as_int(v), 63));
}

__device__ __forceinline__ float dpp_red_sum(float v) {
  int x;
  x = __builtin_amdgcn_update_dpp(__float_as_int(v), __float_as_int(v), 0x111, 0xf, 0xf, false);
  v = v + __int_as_float(x);
  x = __builtin_amdgcn_update_dpp(__float_as_int(v), __float_as_int(v), 0x112, 0xf, 0xf, false);
  v = v + __int_as_float(x);
  x = __builtin_amdgcn_update_dpp(__float_as_int(v), __float_as_int(v), 0x114, 0xf, 0xf, false);
  v = v + __int_as_float(x);
  x = __builtin_amdgcn_update_dpp(__float_as_int(v), __float_as_int(v), 0x118, 0xf, 0xf, false);
  v = v + __int_as_float(x);
  x = __builtin_amdgcn_update_dpp(__float_as_int(v), __float_as_int(v), 0x142, 0xa, 0xf, false);
  v = v + __int_as_float(x);
  x = __builtin_amdgcn_update_dpp(__float_as_int(v), __float_as_int(v), 0x143, 0xc, 0xf, false);
  v = v + __int_as_float(x);
  return __int_as_float(__builtin_amdgcn_readlane(__float_as_int(v), 63));
}

// ---------------- Kernel 0: W -> bf16 hi/lo fragments (B-operand order) ----
// wf[((kk*4+nt)*64+lane)*8+j] = bf16 of W[kk*32+(lane>>4)*8+j][nt*16+(lane&15)]
__global__ __launch_bounds__(256) void prep_w(
    const float* __restrict__ W, unsigned short* __restrict__ wf_hi,
    unsigned short* __restrict__ wf_lo) {
  const int f = blockIdx.x * 256 + threadIdx.x;  // 0..8191
  const int kk = f >> 8;
  const int nt = (f >> 6) & 3;
  const int l = f & 63;
  const int n = nt * 16 + (l & 15);
  const int k0 = kk * 32 + ((l >> 4) << 3);
  short8 hv, lv;
#pragma unroll
  for (int j = 0; j < 8; ++j) {
    const float x = W[(size_t)(k0 + j) * NTAG + n];
    const unsigned short h = f2bf_rne(x);
    hv[j] = (short)h;
    lv[j] = (short)f2bf_rne(x - bf2f(h));
  }
  *reinterpret_cast<short8*>(wf_hi + (size_t)f * 8) = hv;
  *reinterpret_cast<short8*>(wf_lo + (size_t)f * 8) = lv;
}

// ---------------- Kernel 1: scores = (X @ W + b) * mask  (MFMA) ----------
// 512 blocks x 256 thr; each WAVE independently computes a 16-row x 64-col
// tile over full K=1024. NO LDS, NO barriers, NO atomics. A-frags loaded
// directly from X (16 rows x 128B fully covered per kk); B-frags from the
// L2-resident prep'd arrays. Numerics bit-identical to R8 (same convert,
// same per-acc MFMA order: kk ascending, {ah*bh, ah*bl, al*bh}).
__global__ __launch_bounds__(256, 2) void gemm_scores(
    const float* __restrict__ X, const int* __restrict__ mask,
    const unsigned short* __restrict__ wf_hi,
    const unsigned short* __restrict__ wf_lo,
    const float* __restrict__ bias, float* __restrict__ scores) {
  const int lane = threadIdx.x & 63;
  const int wv = threadIdx.x >> 6;
  const int row0 = (blockIdx.x * 4 + wv) * 16;
  const int am = lane & 15;   // A row within tile
  const int aq = lane >> 4;   // k quad: holds k = kk*32 + aq*8 + j

  floatx4 acc[4];
#pragma unroll
  for (int nt = 0; nt < 4; ++nt) acc[nt] = (floatx4)(0.f);

  const float* Xp = X + (size_t)(row0 + am) * DD + aq * 8;

#pragma unroll 4
  for (int kk = 0; kk < 32; ++kk) {
    const float4 xa = *reinterpret_cast<const float4*>(Xp + kk * 32);
    const float4 xb = *reinterpret_cast<const float4*>(Xp + kk * 32 + 4);
    short8 ah, al;
    {
      const float v[8] = {xa.x, xa.y, xa.z, xa.w, xb.x, xb.y, xb.z, xb.w};
#pragma unroll
      for (int e = 0; e < 8; ++e) {
        const unsigned short h = f2bf_rne(v[e]);
        ah[e] = (short)h;
        al[e] = (short)f2bf_rne(v[e] - bf2f(h));
      }
    }
    const size_t fb = (size_t)kk * 2048;  // kk*4*64*8
#pragma unroll
    for (int nt = 0; nt < 4; ++nt) {
      const size_t off = fb + ((size_t)nt * 64 + lane) * 8;
      const short8 bh = *reinterpret_cast<const short8*>(wf_hi + off);
      const short8 bl = *reinterpret_cast<const short8*>(wf_lo + off);
      acc[nt] = __builtin_amdgcn_mfma_f32_16x16x32_bf16(ah, bh, acc[nt], 0, 0, 0);
      acc[nt] = __builtin_amdgcn_mfma_f32_16x16x32_bf16(ah, bl, acc[nt], 0, 0, 0);
      acc[nt] = __builtin_amdgcn_mfma_f32_16x16x32_bf16(al, bh, acc[nt], 0, 0, 0);
    }
  }

  // epilogue: C/D layout col=lane&15, row=(lane>>4)*4+reg
  const int colb = lane & 15;
  const int quad = lane >> 4;
  float bn[4];
#pragma unroll
  for (int nt = 0; nt < 4; ++nt) bn[nt] = bias[nt * 16 + colb];
#pragma unroll
  for (int r = 0; r < 4; ++r) {
    const int row = row0 + quad * 4 + r;
    const float mf = (float)mask[row];
#pragma unroll
    for (int nt = 0; nt < 4; ++nt)
      scores[(size_t)row * 64 + nt * 16 + colb] = (acc[nt][r] + bn[nt]) * mf;
  }
}

// ---------------- Kernel 2: forward passes (single wave; readlane) --------
__global__ __launch_bounds__(64) void crf_forward(
    const float* __restrict__ scores, const int* __restrict__ mask,
    const int* __restrict__ labels, const float* __restrict__ trans,
    const float* __restrict__ startv, const float* __restrict__ endv,
    float* __restrict__ ws_alpha, int* __restrict__ ws_lasttag,
    float* __restrict__ ws_loss) {
  const int lane = threadIdx.x;
  const int role = blockIdx.x >> 6;
  const int b = blockIdx.x & 63;
  const float* sc = scores + (size_t)b * TT * NTAG;
  const int* maskb = mask + b * TT;

  if (role == 0) {
    float tcol[NTAG];  // tcol[i] = trans[i][lane]
#pragma unroll
    for (int i = 0; i < NTAG; ++i) tcol[i] = trans[(size_t)i * NTAG + lane];
    float valpha = startv[lane] + sc[lane];
    float* wsA = ws_alpha + (size_t)b * TT * NTAG;

    float e0 = sc[1 * NTAG + lane], e1 = sc[2 * NTAG + lane];
    float e2 = sc[3 * NTAG + lane], e3 = sc[4 * NTAG + lane];
    int k0 = maskb[1], k1 = maskb[2], k2 = maskb[3], k3 = maskb[4];

    for (int t = 1; t < TT; ++t) {
      wsA[(size_t)(t - 1) * NTAG + lane] = valpha;
      const float emit = e0;
      const int m = k0;
      const int tp = (t + 4 < TT) ? (t + 4) : (TT - 1);
      e0 = e1; e1 = e2; e2 = e3;
      e3 = sc[(size_t)tp * NTAG + lane];
      k0 = k1; k1 = k2; k2 = k3;
      k3 = maskb[tp];

      float m0 = -3.4e38f, m1 = -3.4e38f, m2 = -3.4e38f, m3 = -3.4e38f;
#pragma unroll
      for (int i = 0; i < NTAG; i += 4) {
        m0 = fmaxf(m0, rl(valpha, i + 0) + tcol[i + 0]);
        m1 = fmaxf(m1, rl(valpha, i + 1) + tcol[i + 1]);
        m2 = fmaxf(m2, rl(valpha, i + 2) + tcol[i + 2]);
        m3 = fmaxf(m3, rl(valpha, i + 3) + tcol[i + 3]);
      }
      const float best = fmaxf(fmaxf(m0, m1), fmaxf(m2, m3));
      valpha = m ? (best + emit) : valpha;
    }
    wsA[(size_t)(TT - 1) * NTAG + lane] = valpha;  // final alpha row for bt

    const float fin = valpha + endv[lane];
    const float mx = dpp_red_max(fin);
    const int jlast = (int)__builtin_ctzll(__ballot(fin == mx));
    if (lane == 0) ws_lasttag[b] = jlast;
  } else {
    float ecol[NTAG];  // exp(trans[i][lane])
#pragma unroll
    for (int i = 0; i < NTAG; ++i) ecol[i] = expf(trans[(size_t)i * NTAG + lane]);

    const float alpha0 = startv[lane] + sc[lane];
    const float M0 = dpp_red_max(alpha0);
    float z = expf(alpha0 - M0);  // z = exp(alpha - C)
    float C = M0;

    float e0 = sc[1 * NTAG + lane], e1 = sc[2 * NTAG + lane];
    float e2 = sc[3 * NTAG + lane], e3 = sc[4 * NTAG + lane];
    int k0 = maskb[1], k1 = maskb[2], k2 = maskb[3], k3 = maskb[4];
    float pe = expf(e0);

    for (int t = 1; t < TT; ++t) {
      const float pec = pe;
      const int m = k0;
      const int tp = (t + 4 < TT) ? (t + 4) : (TT - 1);
      e0 = e1; e1 = e2; e2 = e3;
      e3 = sc[(size_t)tp * NTAG + lane];
      k0 = k1; k1 = k2; k2 = k3;
      k3 = maskb[tp];
      pe = expf(e0);  // off critical path

      float s0 = 0.f, s1 = 0.f, s2 = 0.f, s3 = 0.f;
#pragma unroll
      for (int i = 0; i < NTAG; i += 4) {
        s0 = fmaf(rl(z, i + 0), ecol[i + 0], s0);
        s1 = fmaf(rl(z, i + 1), ecol[i + 1], s1);
        s2 = fmaf(rl(z, i + 2), ecol[i + 2], s2);
        s3 = fmaf(rl(z, i + 3), ecol[i + 3], s3);
      }
      const float inner = (s0 + s1) + (s2 + s3);
      z = m ? (inner * pec) : z;

      if ((t & 7) == 0) {  // renormalize; growth bounded, fp32-safe
        const float s = dpp_red_sum(z);
        const float r = __builtin_amdgcn_rcpf(s);
        z *= r;
        C += logf(s);
      }
    }
    const float av = logf(z) + C;
    const float fv = av + endv[lane];
    const float M2 = dpp_red_max(fv);
    const float sSum = dpp_red_sum(expf(fv - M2));
    const float log_z = logf(sSum) + M2;

    float g = 0.f, msumf = 0.f;
    for (int t = lane; t < TT; t += 64) {
      const int lab = labels[b * TT + t];
      const float mf = (float)maskb[t];
      msumf += mf;
      g += sc[(size_t)t * NTAG + lab] * mf;
      if (t >= 1) {
        const int labp = labels[b * TT + t - 1];
        g += trans[(size_t)labp * NTAG + lab] * mf;
      }
    }
    g = dpp_red_sum(g);
    const float msum = dpp_red_sum(msumf);
    const int last_idx = (int)msum - 1;
    g += startv[labels[b * TT]] + endv[labels[b * TT + last_idx]];
    if (lane == 0) ws_loss[b] = log_z - g;
  }
}

// ---------------- Kernel 3: backtrack via ballot-against-target ----------
// Winner i* satisfies round((alpha_s[i]+T[i][j]) + emit_{s+1}[j]) ==
// alpha_{s+1}[j] bit-exactly (fmax selects an input exactly; monotone
// rounding => value identity). Comparing the SUMMED scores also reproduces
// jnp.argmax's first-index tie rule over sc = (alpha+T)+emit. No DPP
// reduction on the chain: LDS read + 2 adds + ballot + ctz (~150 cyc/step).
__global__ __launch_bounds__(64) void viterbi_bt(
    const float* __restrict__ ws_alpha, const int* __restrict__ ws_lasttag,
    const float* __restrict__ scores, const int* __restrict__ mask,
    const float* __restrict__ trans, float* __restrict__ out_tags) {
  __shared__ float tP[NTAG * 65];  // tP[i*65+j] = trans[i][j]; 2-way alias: free
  __shared__ int mk[TT];
  __shared__ unsigned char tagb[TT];
  const int lane = threadIdx.x;
  const int b = blockIdx.x;
  const float* sc = scores + (size_t)b * TT * NTAG;

#pragma unroll
  for (int i = 0; i < NTAG; ++i) tP[i * 65 + lane] = trans[(size_t)i * NTAG + lane];
  for (int t = lane; t < TT; t += 64) mk[t] = mask[b * TT + t];

  const float* wsA = ws_alpha + (size_t)b * TT * NTAG;
  int jcur = ws_lasttag[b];
  if (lane == 0) tagb[TT - 1] = (unsigned char)jcur;

  // rotating prefetch: r0..r4 = alpha rows {s+1, s, s-1, s-2, s-3};
  // e0..e3 = sc rows {s+1, s, s-1, s-2}
  float r0 = wsA[(size_t)(TT - 1) * NTAG + lane];
  float r1 = wsA[(size_t)(TT - 2) * NTAG + lane];
  float r2 = wsA[(size_t)(TT - 3) * NTAG + lane];
  float r3 = wsA[(size_t)(TT - 4) * NTAG + lane];
  float r4 = wsA[(size_t)(TT - 5) * NTAG + lane];
  float e0 = sc[(size_t)(TT - 1) * NTAG + lane];
  float e1 = sc[(size_t)(TT - 2) * NTAG + lane];
  float e2 = sc[(size_t)(TT - 3) * NTAG + lane];
  float e3 = sc[(size_t)(TT - 4) * NTAG + lane];

  for (int s = TT - 2; s >= 0; --s) {
    const float anext = r0;  // alpha_{s+1}
    const float ac = r1;     // alpha_s
    const float erow = e0;   // sc row s+1
    r0 = r1; r1 = r2; r2 = r3; r3 = r4;
    const int sp = (s >= 4) ? (s - 4) : 0;  // regs held {s+1..s-3}; refill s-4
    r4 = wsA[(size_t)sp * NTAG + lane];
    e0 = e1; e1 = e2; e2 = e3;
    const int ep = (s >= 3) ? (s - 3) : 0;
    e3 = sc[(size_t)ep * NTAG + lane];

    if (mk[s + 1]) {
      const float target = rl(anext, jcur);
      const float emitv = rl(erow, jcur);
      const float cand = (ac + tP[lane * 65 + jcur]) + emitv;  // same op order as ref
      const unsigned long long bal = __ballot(cand == target);
      if (bal) jcur = (int)__builtin_ctzll(bal);
    }
    if (lane == 0) tagb[s] = (unsigned char)jcur;
  }

  for (int t = lane; t < TT; t += 64)
    out_tags[b * TT + t] = (float)(mk[t] ? (int)tagb[t] : 0);
}

// ---------------- Kernel 4: loss = mean(log_z - gold) ----------------
__global__ __launch_bounds__(64) void loss_mean(const float* __restrict__ ws_loss,
                                                float* __restrict__ out) {
  const float v = ws_loss[threadIdx.x];
  const float s = dpp_red_sum(v);
  if (threadIdx.x == 0) out[0] = s * (1.0f / 64.0f);
}

extern "C" void kernel_launch(void* const* d_in, const int* in_sizes, int n_in,
                              void* d_out, int out_size, void* d_ws, size_t ws_size,
                              hipStream_t stream) {
  const float* X = (const float*)d_in[0];
  const int* mask = (const int*)d_in[1];
  const int* labels = (const int*)d_in[2];
  const float* W = (const float*)d_in[3];
  const float* bias = (const float*)d_in[4];
  const float* trans = (const float*)d_in[5];
  const float* startv = (const float*)d_in[6];
  const float* endv = (const float*)d_in[7];

  float* out = (float*)d_out;
  float* scores = out;
  float* out_tags = out + TAGS_OFF;
  float* out_loss = out + LOSS_OFF;

  unsigned short* wf_hi = (unsigned short*)d_ws;        // 65536 bf16
  unsigned short* wf_lo = wf_hi + 65536;                // 65536 bf16
  float* ws_alpha = (float*)(wf_lo + 65536);            // 64*512*64 fp32 (TT rows now)
  int* ws_lasttag = (int*)(ws_alpha + (size_t)BB * TT * NTAG);
  float* ws_loss = (float*)(ws_lasttag + BB);

  prep_w<<<32, 256, 0, stream>>>(W, wf_hi, wf_lo);
  gemm_scores<<<512, 256, 0, stream>>>(X, mask, wf_hi, wf_lo, bias, scores);
  crf_forward<<<128, 64, 0, stream>>>(scores, mask, labels, trans, startv, endv,
                                      ws_alpha, ws_lasttag, ws_loss);
  viterbi_bt<<<64, 64, 0, stream>>>(ws_alpha, ws_lasttag, scores, mask, trans, out_tags);
  loss_mean<<<1, 64, 0, stream>>>(ws_loss, out_loss);
}